// Round 17
// baseline (170.163 us; speedup 1.0000x reference)
//
#include <hip/hip_runtime.h>
#include <math.h>

namespace {

constexpr int Bb = 4, Nn = 2048, Cc = 512, Hh = 8, Dd = 64, Ss = 40, Uu = 40;
constexpr int M_ROWS = Bb * Nn; // 8192
constexpr int BH = Bb * Hh;     // 32
constexpr int DV_ROWS = 1408;   // 1280 attn rows + 4 vmean rows, padded to 11*128

typedef __attribute__((ext_vector_type(8))) short short8;
typedef __attribute__((ext_vector_type(4))) float f32x4;

__device__ inline unsigned short f2bf(float f) {
  union { float f; unsigned u; } v; v.f = f;
  unsigned r = (v.u + 0x7fffu + ((v.u >> 16) & 1u)) >> 16;
  return (unsigned short)r;
}
__device__ inline float bf2f(unsigned short h) {
  union { unsigned u; float f; } v; v.u = ((unsigned)h) << 16;
  return v.f;
}

// ---------- split x into bf16 hi/lo AND build transposed split weights ----------
__global__ __launch_bounds__(256) void convert_all(
    const float* __restrict__ x, const float* __restrict__ Wq,
    const float* __restrict__ Wk, const float* __restrict__ Wv,
    const float* __restrict__ Wo,
    unsigned short* __restrict__ xh, unsigned short* __restrict__ xl,
    unsigned short* __restrict__ WTh, unsigned short* __restrict__ WTl)
{
  if (blockIdx.x < 4096) {
    size_t i = ((size_t)blockIdx.x * 256 + threadIdx.x) * 4;
    float4 v = *(const float4*)(x + i);
    ushort4 h, l;
    h.x = f2bf(v.x); l.x = f2bf(v.x - bf2f(h.x));
    h.y = f2bf(v.y); l.y = f2bf(v.y - bf2f(h.y));
    h.z = f2bf(v.z); l.z = f2bf(v.z - bf2f(h.z));
    h.w = f2bf(v.w); l.w = f2bf(v.w - bf2f(h.w));
    *(ushort4*)(xh + i) = h;
    *(ushort4*)(xl + i) = l;
  } else {
    int wb = blockIdx.x - 4096;       // 0..255
    int which = wb >> 6;
    int tile = wb & 63;
    int tr = tile >> 3, tc = tile & 7;
    const float* Wsrc = which == 0 ? Wq : (which == 1 ? Wk : (which == 2 ? Wv : Wo));
    __shared__ float tileS[64][65];
    int t = threadIdx.x;
    int r0 = t >> 4;
    int c0 = (t & 15) * 4;
    #pragma unroll
    for (int i = 0; i < 4; ++i) {
      int r = r0 + i * 16;
      float4 v = *(const float4*)(Wsrc + (size_t)(tr * 64 + r) * 512 + tc * 64 + c0);
      tileS[r][c0] = v.x; tileS[r][c0 + 1] = v.y;
      tileS[r][c0 + 2] = v.z; tileS[r][c0 + 3] = v.w;
    }
    __syncthreads();
    #pragma unroll
    for (int i = 0; i < 4; ++i) {
      int c = r0 + i * 16;
      float4 v = make_float4(tileS[c0][c], tileS[c0 + 1][c],
                             tileS[c0 + 2][c], tileS[c0 + 3][c]);
      ushort4 hh, ll;
      hh.x = f2bf(v.x); ll.x = f2bf(v.x - bf2f(hh.x));
      hh.y = f2bf(v.y); ll.y = f2bf(v.y - bf2f(hh.y));
      hh.z = f2bf(v.z); ll.z = f2bf(v.z - bf2f(hh.z));
      hh.w = f2bf(v.w); ll.w = f2bf(v.w - bf2f(hh.w));
      size_t off = (size_t)(which * 512 + tc * 64 + c) * 512 + tr * 64 + c0;
      *(ushort4*)(WTh + off) = hh;
      *(ushort4*)(WTl + off) = ll;
    }
  }
}

// ---------- QKV GEMM: 256x128 tile, 512 threads, R12-proven (47us) ----------
__global__ __launch_bounds__(512) void gemm_qkv(
    const unsigned short* __restrict__ xh, const unsigned short* __restrict__ xl,
    const unsigned short* __restrict__ WThp, const unsigned short* __restrict__ WTlp,
    const float* __restrict__ bq, const float* __restrict__ bk, const float* __restrict__ bv,
    float* __restrict__ o0, float* __restrict__ o1, float* __restrict__ o2)
{
  __shared__ __align__(16) unsigned short Ah[256 * 32];
  __shared__ __align__(16) unsigned short Al[256 * 32];
  __shared__ __align__(16) unsigned short Bh[128 * 32];
  __shared__ __align__(16) unsigned short Bl[128 * 32];
  int tid = threadIdx.x;
  int lane = tid & 63, w = tid >> 6;
  int bm = blockIdx.x * 256, bn = blockIdx.y * 128;

  f32x4 acc[4][4];
  #pragma unroll
  for (int i = 0; i < 4; ++i)
    #pragma unroll
    for (int j = 0; j < 4; ++j)
      #pragma unroll
      for (int r = 0; r < 4; ++r) acc[i][j][r] = 0.f;

  int wm = (w >> 1) * 64, wn = (w & 1) * 64;
  int lm = lane & 15, lg = lane >> 4;

  int srow = tid >> 2;                       // 0..127
  int cs = (tid & 3) ^ ((srow >> 1) & 3);    // pre-swizzled source chunk
  size_t a0 = (size_t)(bm + srow) * 512 + cs * 8;
  size_t a1 = a0 + (size_t)128 * 512;
  size_t b0 = (size_t)(bn + srow) * 512 + cs * 8;
  unsigned d0 = w * 1024;

#define GLDS(gp, lp) __builtin_amdgcn_global_load_lds( \
    (const __attribute__((address_space(1))) void*)(gp), \
    (__attribute__((address_space(3))) void*)(lp), 16, 0, 0)

  for (int kt = 0; kt < 16; ++kt) {
    int k0 = kt * 32;
    GLDS(xh   + a0 + k0, (char*)Ah + d0);
    GLDS(xh   + a1 + k0, (char*)Ah + 8192 + d0);
    GLDS(xl   + a0 + k0, (char*)Al + d0);
    GLDS(xl   + a1 + k0, (char*)Al + 8192 + d0);
    GLDS(WThp + b0 + k0, (char*)Bh + d0);
    GLDS(WTlp + b0 + k0, (char*)Bl + d0);
    __syncthreads();

    short8 afh[4], bgh[4], afl[4], bgl[4];
    #pragma unroll
    for (int i = 0; i < 4; ++i) {
      int R = wm + i * 16 + lm;
      afh[i] = *(const short8*)(Ah + R * 32 + ((lg ^ ((R >> 1) & 3)) * 8));
    }
    #pragma unroll
    for (int j = 0; j < 4; ++j) {
      int R = wn + j * 16 + lm;
      bgh[j] = *(const short8*)(Bh + R * 32 + ((lg ^ ((R >> 1) & 3)) * 8));
    }
    #pragma unroll
    for (int i = 0; i < 4; ++i)
      #pragma unroll
      for (int j = 0; j < 4; ++j)
        acc[i][j] = __builtin_amdgcn_mfma_f32_16x16x32_bf16(afh[i], bgh[j], acc[i][j], 0, 0, 0);

    #pragma unroll
    for (int i = 0; i < 4; ++i) {
      int R = wm + i * 16 + lm;
      afl[i] = *(const short8*)(Al + R * 32 + ((lg ^ ((R >> 1) & 3)) * 8));
    }
    #pragma unroll
    for (int i = 0; i < 4; ++i)
      #pragma unroll
      for (int j = 0; j < 4; ++j)
        acc[i][j] = __builtin_amdgcn_mfma_f32_16x16x32_bf16(afl[i], bgh[j], acc[i][j], 0, 0, 0);

    #pragma unroll
    for (int j = 0; j < 4; ++j) {
      int R = wn + j * 16 + lm;
      bgl[j] = *(const short8*)(Bl + R * 32 + ((lg ^ ((R >> 1) & 3)) * 8));
    }
    #pragma unroll
    for (int i = 0; i < 4; ++i)
      #pragma unroll
      for (int j = 0; j < 4; ++j)
        acc[i][j] = __builtin_amdgcn_mfma_f32_16x16x32_bf16(afh[i], bgl[j], acc[i][j], 0, 0, 0);

    __syncthreads();
  }
#undef GLDS

  #pragma unroll
  for (int j = 0; j < 4; ++j) {
    int n = bn + wn + j * 16 + lm;
    float bias = n < 512 ? bq[n] : (n < 1024 ? bk[n - 512] : bv[n - 1024]);
    int tensor = n >> 9, h = (n >> 6) & 7, d = n & 63;
    float* op = tensor == 0 ? o0 : (tensor == 1 ? o1 : o2);
    #pragma unroll
    for (int i = 0; i < 4; ++i) {
      #pragma unroll
      for (int r = 0; r < 4; ++r) {
        int m = bm + wm + i * 16 + lg * 4 + r;
        int b = m >> 11, nn = m & 2047;
        op[((size_t)(b * Hh + h) * Nn + nn) * Dd + d] = acc[i][j][r] + bias;
      }
    }
  }
}

// ---------- dout GEMM: 128x128 tile, 256 threads (R9-proven geometry) ----------
__global__ __launch_bounds__(256) void gemm_dout(
    const unsigned short* __restrict__ xh, const unsigned short* __restrict__ xl,
    const unsigned short* __restrict__ WThp, const unsigned short* __restrict__ WTlp,
    float* __restrict__ o0)
{
  __shared__ __align__(16) unsigned short Ah[128 * 32];
  __shared__ __align__(16) unsigned short Al[128 * 32];
  __shared__ __align__(16) unsigned short Bh[128 * 32];
  __shared__ __align__(16) unsigned short Bl[128 * 32];
  int tid = threadIdx.x;
  int lane = tid & 63, w = tid >> 6;
  int bm = blockIdx.x * 128, bn = blockIdx.y * 128;

  f32x4 acc[4][4];
  #pragma unroll
  for (int i = 0; i < 4; ++i)
    #pragma unroll
    for (int j = 0; j < 4; ++j)
      #pragma unroll
      for (int r = 0; r < 4; ++r) acc[i][j][r] = 0.f;

  int wm = (w >> 1) * 64, wn = (w & 1) * 64;
  int lm = lane & 15, lg = lane >> 4;

  int srow = lane >> 2;
  int row0 = w * 16 + srow;
  int row1 = row0 + 64;
  int cs0 = (lane & 3) ^ ((row0 >> 1) & 3);
  int cs1 = (lane & 3) ^ ((row1 >> 1) & 3);
  size_t a0 = (size_t)(bm + row0) * 512 + cs0 * 8;
  size_t a1 = (size_t)(bm + row1) * 512 + cs1 * 8;
  size_t b0 = (size_t)(bn + row0) * 512 + cs0 * 8;
  size_t b1 = (size_t)(bn + row1) * 512 + cs1 * 8;
  unsigned d0 = w * 1024;

#define GLDS(gp, lp) __builtin_amdgcn_global_load_lds( \
    (const __attribute__((address_space(1))) void*)(gp), \
    (__attribute__((address_space(3))) void*)(lp), 16, 0, 0)

  for (int kt = 0; kt < 16; ++kt) {
    int k0 = kt * 32;
    GLDS(xh   + a0 + k0, (char*)Ah + d0);
    GLDS(xh   + a1 + k0, (char*)Ah + 4096 + d0);
    GLDS(xl   + a0 + k0, (char*)Al + d0);
    GLDS(xl   + a1 + k0, (char*)Al + 4096 + d0);
    GLDS(WThp + b0 + k0, (char*)Bh + d0);
    GLDS(WThp + b1 + k0, (char*)Bh + 4096 + d0);
    GLDS(WTlp + b0 + k0, (char*)Bl + d0);
    GLDS(WTlp + b1 + k0, (char*)Bl + 4096 + d0);
    __syncthreads();

    short8 afh[4], bgh[4], afl[4], bgl[4];
    #pragma unroll
    for (int i = 0; i < 4; ++i) {
      int R = wm + i * 16 + lm;
      afh[i] = *(const short8*)(Ah + R * 32 + ((lg ^ ((R >> 1) & 3)) * 8));
    }
    #pragma unroll
    for (int j = 0; j < 4; ++j) {
      int R = wn + j * 16 + lm;
      bgh[j] = *(const short8*)(Bh + R * 32 + ((lg ^ ((R >> 1) & 3)) * 8));
    }
    #pragma unroll
    for (int i = 0; i < 4; ++i)
      #pragma unroll
      for (int j = 0; j < 4; ++j)
        acc[i][j] = __builtin_amdgcn_mfma_f32_16x16x32_bf16(afh[i], bgh[j], acc[i][j], 0, 0, 0);

    #pragma unroll
    for (int i = 0; i < 4; ++i) {
      int R = wm + i * 16 + lm;
      afl[i] = *(const short8*)(Al + R * 32 + ((lg ^ ((R >> 1) & 3)) * 8));
    }
    #pragma unroll
    for (int i = 0; i < 4; ++i)
      #pragma unroll
      for (int j = 0; j < 4; ++j)
        acc[i][j] = __builtin_amdgcn_mfma_f32_16x16x32_bf16(afl[i], bgh[j], acc[i][j], 0, 0, 0);

    #pragma unroll
    for (int j = 0; j < 4; ++j) {
      int R = wn + j * 16 + lm;
      bgl[j] = *(const short8*)(Bl + R * 32 + ((lg ^ ((R >> 1) & 3)) * 8));
    }
    #pragma unroll
    for (int i = 0; i < 4; ++i)
      #pragma unroll
      for (int j = 0; j < 4; ++j)
        acc[i][j] = __builtin_amdgcn_mfma_f32_16x16x32_bf16(afh[i], bgl[j], acc[i][j], 0, 0, 0);

    __syncthreads();
  }
#undef GLDS

  #pragma unroll
  for (int j = 0; j < 4; ++j) {
    int n = bn + wn + j * 16 + lm;
    #pragma unroll
    for (int i = 0; i < 4; ++i) {
      #pragma unroll
      for (int r = 0; r < 4; ++r) {
        int m = bm + wm + i * 16 + lg * 4 + r;
        o0[(size_t)m * 512 + n] = acc[i][j][r];
      }
    }
  }
}

// ---------- sampled QK^T -> M (blocks 0..4095, 4 l's/wave) + vmean (4096..4127) ----------
// R17: doubled grid for TLP (R7-proven mechanism). Same loads, same bh->XCD pin.
__global__ __launch_bounds__(256) void sampled_vmean_kernel(
    const float* __restrict__ q, const float* __restrict__ k,
    const int* __restrict__ idx, float* __restrict__ Mout,
    const float* __restrict__ v, float* __restrict__ vmean, int* __restrict__ map)
{
  int p = blockIdx.x;
  int t = threadIdx.x;
  if (p >= 4096) {
    int bh = p - 4096;
    for (int i = t; i < Nn; i += 256) map[bh * Nn + i] = -1;
    int d = t & 63, chunk = t >> 6;
    const float* base = v + (size_t)bh * Nn * Dd;
    float s = 0.f;
    for (int n = chunk * 512; n < (chunk + 1) * 512; ++n) s += base[(size_t)n * Dd + d];
    __shared__ float part[4][64];
    part[chunk][d] = s;
    __syncthreads();
    if (t < 64)
      vmean[bh * Dd + t] = (part[0][t] + part[1][t] + part[2][t] + part[3][t]) * (1.f / (float)Nn);
    return;
  }
  int xcd = p & 7, j = p >> 3;
  int chunk = j & 127;                 // 128 chunks of 16 l's
  int bh = (j >> 7) * 8 + xcd;
  int w = t >> 6, lane = t & 63;
  int g = lane >> 2, dq = lane & 3;

  const float* kb = k + (size_t)bh * Nn * Dd;

  for (int li = 0; li < 4; ++li) {
    int l = chunk * 16 + w * 4 + li;
    const float* qrow = q + ((size_t)bh * Nn + l) * Dd + dq * 4;
    float4 qv[4];
    #pragma unroll
    for (int i = 0; i < 4; ++i) qv[i] = *(const float4*)(qrow + i * 16);
    float mx = -INFINITY, sm = 0.f;
    #pragma unroll
    for (int pass = 0; pass < 3; ++pass) {
      int s = pass * 16 + g;
      bool valid = (s < Ss);
      float dot = 0.f;
      if (valid) {
        int kr = idx[l * Ss + s];
        const float* krow = kb + (size_t)kr * Dd + dq * 4;
        #pragma unroll
        for (int i = 0; i < 4; ++i) {
          float4 kv = *(const float4*)(krow + i * 16);
          dot += kv.x * qv[i].x + kv.y * qv[i].y + kv.z * qv[i].z + kv.w * qv[i].w;
        }
      }
      dot += __shfl_xor(dot, 1);
      dot += __shfl_xor(dot, 2);
      if (valid) { mx = fmaxf(mx, dot); sm += dot; }
    }
    #pragma unroll
    for (int o = 4; o < 64; o <<= 1) {
      mx = fmaxf(mx, __shfl_xor(mx, o));
      sm += __shfl_xor(sm, o);
    }
    if (lane == 0) Mout[(size_t)bh * Nn + l] = mx - sm * (1.f / (float)Nn);
  }
}

// ---------- top-40 per (b,h): exact radix-select ----------
__global__ __launch_bounds__(256) void topk_kernel(
    const float* __restrict__ Min, int* __restrict__ M_top)
{
  int bh = blockIdx.x, t = threadIdx.x;
  __shared__ unsigned keys[2048];
  __shared__ unsigned hist[256];
  __shared__ unsigned cum[257];
  __shared__ unsigned sh_b, sh_k, sh_cnt, sh_eqcnt;
  __shared__ int eqlist[2048];

  #pragma unroll
  for (int j = 0; j < 8; ++j) {
    int ix = t + j * 256;
    unsigned u = __float_as_uint(Min[(size_t)bh * Nn + ix]);
    keys[ix] = u ^ (((unsigned)((int)u >> 31)) | 0x80000000u);
  }
  if (t == 0) { sh_k = Uu; sh_cnt = 0; sh_eqcnt = 0; }
  if (t == 255) cum[256] = 0;
  __syncthreads();

  unsigned known = 0;
  for (int shift = 24; shift >= 0; shift -= 8) {
    hist[t] = 0;
    __syncthreads();
    unsigned mask_hi = (shift == 24) ? 0u : (0xFFFFFFFFu << (shift + 8));
    #pragma unroll
    for (int j = 0; j < 8; ++j) {
      unsigned key = keys[t + j * 256];
      if ((key & mask_hi) == known)
        atomicAdd(&hist[(key >> shift) & 255], 1u);
    }
    __syncthreads();
    cum[t] = hist[t];
    __syncthreads();
    for (int off = 1; off < 256; off <<= 1) {
      unsigned add = (t + off < 256) ? cum[t + off] : 0u;
      __syncthreads();
      cum[t] += add;
      __syncthreads();
    }
    unsigned kcur = sh_k;
    if (cum[t] >= kcur && cum[t + 1] < kcur) sh_b = (unsigned)t;
    __syncthreads();
    unsigned b = sh_b;
    if (t == 0) sh_k = kcur - cum[b + 1];
    known |= (b << shift);
    __syncthreads();
  }

  unsigned T = known;
  #pragma unroll
  for (int j = 0; j < 8; ++j) {
    int ix = t + j * 256;
    unsigned key = keys[ix];
    if (key > T) {
      unsigned slot = atomicAdd(&sh_cnt, 1u);
      M_top[bh * Uu + slot] = ix;
    } else if (key == T) {
      unsigned e = atomicAdd(&sh_eqcnt, 1u);
      eqlist[e] = ix;
    }
  }
  __syncthreads();
  if (t == 0) {
    unsigned kk = sh_k;
    unsigned m = sh_eqcnt;
    unsigned base = sh_cnt;
    for (unsigned r = 0; r < kk; ++r) {
      int best = 0x7FFFFFFF, bj = 0;
      for (unsigned j2 = 0; j2 < m; ++j2)
        if (eqlist[j2] < best) { best = eqlist[j2]; bj = (int)j2; }
      M_top[bh * Uu + base + r] = best;
      eqlist[bj] = 0x7FFFFFFF;
    }
  }
}

// ---------- fused scores+softmax+PV partials, per (64-col chunk, bh) ----------
__global__ __launch_bounds__(256) void fused_attn_kernel(
    const float* __restrict__ q, const float* __restrict__ k, const float* __restrict__ v,
    const int* __restrict__ M_top, float* __restrict__ pm, float* __restrict__ ps,
    float* __restrict__ partial)
{
  int chunk = blockIdx.x, bh = blockIdx.y, t = threadIdx.x;
  __shared__ float qs[40][64];
  __shared__ float S[40][64];
  if (t < 160) {
    int u = t >> 2, p = (t & 3) * 16;
    int r = M_top[bh * Uu + u];
    const float4* src = (const float4*)(q + ((size_t)bh * Nn + r) * Dd + p);
    *(float4*)&qs[u][p + 0]  = src[0];
    *(float4*)&qs[u][p + 4]  = src[1];
    *(float4*)&qs[u][p + 8]  = src[2];
    *(float4*)&qs[u][p + 12] = src[3];
  }
  __syncthreads();

  int nl = t & 63, w = t >> 6;
  {
    int n = chunk * 64 + nl;
    const float4* krow = (const float4*)(k + ((size_t)bh * Nn + n) * Dd);
    float acc[10];
    #pragma unroll
    for (int uu = 0; uu < 10; ++uu) acc[uu] = 0.f;
    #pragma unroll
    for (int d4 = 0; d4 < 16; ++d4) {
      float4 kv = krow[d4];
      #pragma unroll
      for (int uu = 0; uu < 10; ++uu) {
        float4 qv = *(const float4*)&qs[w * 10 + uu][d4 * 4];
        acc[uu] += qv.x * kv.x + qv.y * kv.y + qv.z * kv.z + qv.w * kv.w;
      }
    }
    #pragma unroll
    for (int uu = 0; uu < 10; ++uu) S[w * 10 + uu][nl] = acc[uu] * 0.125f;
  }

  #pragma unroll
  for (int r = 0; r < 10; ++r) {
    int u = w * 10 + r;
    float v0 = S[u][nl];
    float m = v0;
    #pragma unroll
    for (int o = 1; o < 64; o <<= 1) m = fmaxf(m, __shfl_xor(m, o));
    float e0 = expf(v0 - m);
    S[u][nl] = e0;
    float sum = e0;
    #pragma unroll
    for (int o = 1; o < 64; o <<= 1) sum += __shfl_xor(sum, o);
    if (nl == 0) {
      pm[(bh * 32 + chunk) * Uu + u] = m;
      ps[(bh * 32 + chunk) * Uu + u] = sum;
    }
  }

  float acc2[10];
  #pragma unroll
  for (int uu = 0; uu < 10; ++uu) acc2[uu] = 0.f;
  const float* vb = v + ((size_t)bh * Nn + chunk * 64) * Dd + nl;
  for (int i = 0; i < 64; ++i) {
    float vv = vb[(size_t)i * Dd];
    #pragma unroll
    for (int uu = 0; uu < 10; ++uu) acc2[uu] = fmaf(S[w * 10 + uu][i], vv, acc2[uu]);
  }
  #pragma unroll
  for (int uu = 0; uu < 10; ++uu) {
    int u = w * 10 + uu;
    partial[(((size_t)bh * Uu + u) * 32 + chunk) * 64 + nl] = acc2[uu];
  }
}

// ---------- combine partials -> dvF rows; blocks >=1280 emit vmean rows ----------
__global__ __launch_bounds__(64) void combine_lite(
    const float* __restrict__ pm, const float* __restrict__ ps,
    const float* __restrict__ partial, const float* __restrict__ vmean,
    const int* __restrict__ M_top,
    unsigned short* __restrict__ dvh, unsigned short* __restrict__ dvl,
    int* __restrict__ map)
{
  int bhu = blockIdx.x;
  int lane = threadIdx.x;

  if (bhu >= BH * Uu) {
    int b = bhu - BH * Uu;
    #pragma unroll
    for (int cc = 0; cc < 8; ++cc) {
      float v = vmean[(b * 8 + cc) * 64 + lane];
      unsigned short hb = f2bf(v);
      dvh[(size_t)bhu * 512 + cc * 64 + lane] = hb;
      dvl[(size_t)bhu * 512 + cc * 64 + lane] = f2bf(v - bf2f(hb));
    }
    return;
  }

  int bh = bhu / Uu, u = bhu % Uu, h = bh & 7;
  float pmv[32];
  float m = -INFINITY;
  #pragma unroll
  for (int c = 0; c < 32; ++c) {
    pmv[c] = pm[(bh * 32 + c) * Uu + u];
    m = fmaxf(m, pmv[c]);
  }
  float w32[32], Z = 0.f;
  #pragma unroll
  for (int c = 0; c < 32; ++c) {
    w32[c] = expf(pmv[c] - m);
    Z += w32[c] * ps[(bh * 32 + c) * Uu + u];
  }

  const float* pb = partial + (size_t)bhu * 2048;
  float s = 0.f;
  #pragma unroll
  for (int c = 0; c < 32; ++c)
    s = fmaf(pb[c * 64 + lane], w32[c], s);

  float dv = s / Z - vmean[bh * Dd + lane];
  unsigned short hbits = f2bf(dv);
  unsigned short lbits = f2bf(dv - bf2f(hbits));

  #pragma unroll
  for (int cc = 0; cc < 8; ++cc) {
    int c = cc * 64 + lane;
    bool mine = (cc == h);
    dvh[(size_t)bhu * 512 + c] = mine ? hbits : (unsigned short)0;
    dvl[(size_t)bhu * 512 + c] = mine ? lbits : (unsigned short)0;
  }
  if (lane == 0) map[bh * Nn + M_top[bhu]] = bhu;
}

// ---------- assemble out rows (base = dout row 1280+b, + bo) ----------
__global__ __launch_bounds__(256) void assemble_kernel(
    const int* __restrict__ map, const float* __restrict__ dout,
    const float* __restrict__ bo, float* __restrict__ out)
{
  int t = threadIdx.x;
  int row = blockIdx.x * 4 + (t >> 6);
  int lane = t & 63;
  int b = row >> 11, n = row & 2047;
  const float* bp = dout + (size_t)(BH * Uu + b) * 512;
  float4 a0 = *(const float4*)(bp + lane * 4);
  float4 a1 = *(const float4*)(bp + 256 + lane * 4);
  float4 o0 = *(const float4*)(bo + lane * 4);
  float4 o1 = *(const float4*)(bo + 256 + lane * 4);
  a0.x += o0.x; a0.y += o0.y; a0.z += o0.z; a0.w += o0.w;
  a1.x += o1.x; a1.y += o1.y; a1.z += o1.z; a1.w += o1.w;
  for (int h = 0; h < 8; ++h) {
    int mi = map[(b * Hh + h) * Nn + n];
    if (mi >= 0) {
      const float* dp = dout + (size_t)mi * 512;
      float4 d0 = *(const float4*)(dp + lane * 4);
      float4 d1 = *(const float4*)(dp + 256 + lane * 4);
      a0.x += d0.x; a0.y += d0.y; a0.z += d0.z; a0.w += d0.w;
      a1.x += d1.x; a1.y += d1.y; a1.z += d1.z; a1.w += d1.w;
    }
  }
  *(float4*)(out + (size_t)row * 512 + lane * 4) = a0;
  *(float4*)(out + (size_t)row * 512 + 256 + lane * 4) = a1;
}

} // namespace

extern "C" void kernel_launch(void* const* d_in, const int* in_sizes, int n_in,
                              void* d_out, int out_size, void* d_ws, size_t ws_size,
                              hipStream_t stream) {
  const float* x  = (const float*)d_in[0];
  const float* Wq = (const float*)d_in[1];
  const float* bq = (const float*)d_in[2];
  const float* Wk = (const float*)d_in[3];
  const float* bk = (const float*)d_in[4];
  const float* Wv = (const float*)d_in[5];
  const float* bv = (const float*)d_in[6];
  const float* Wo = (const float*)d_in[7];
  const float* bo = (const float*)d_in[8];
  const int* idx  = (const int*)d_in[9];
  float* out = (float*)d_out;

  float* ws = (float*)d_ws;
  float* q      = ws;                       // 4,194,304 f
  float* kbuf   = ws + 4194304;
  float* vbuf   = ws + 8388608;
  float* Mbuf   = ws + 12582912;            // 65,536 f
  float* vmean  = ws + 12648448;            // 2,048 f
  float* pm     = ws + 12650496;            // 40,960 f [32][32][40]
  float* ps     = ws + 12691456;            // 40,960 f
  float* dout   = ws + 12732416;            // 720,896 f [1408][512]
  int*   M_top  = (int*)(ws + 13453312);    // 1,280
  int*   map    = (int*)(ws + 13454592);    // 65,536
  unsigned short* dvh = (unsigned short*)(ws + 13520128); // 1408*512 u16
  unsigned short* dvl = (unsigned short*)(ws + 13880576);
  unsigned short* xh  = (unsigned short*)(ws + 14241024); // 8192*512 u16
  unsigned short* xl  = (unsigned short*)(ws + 16338176);
  unsigned short* WTh = (unsigned short*)(ws + 18435328); // 2048*512 u16
  unsigned short* WTl = (unsigned short*)(ws + 18959616);
  float* partial = ws + 14241024;           // overlays xh/xl after gemm_qkv

  convert_all<<<4096 + 256, 256, 0, stream>>>(x, Wq, Wk, Wv, Wo, xh, xl, WTh, WTl);

  gemm_qkv<<<dim3(32, 12), 512, 0, stream>>>(
      xh, xl, WTh, WTl, bq, bk, bv, q, kbuf, vbuf);

  sampled_vmean_kernel<<<4096 + 32, 256, 0, stream>>>(
      q, kbuf, idx, Mbuf, vbuf, vmean, map);

  topk_kernel<<<BH, 256, 0, stream>>>(Mbuf, M_top);

  fused_attn_kernel<<<dim3(32, BH), 256, 0, stream>>>(q, kbuf, vbuf, M_top, pm, ps, partial);

  combine_lite<<<BH * Uu + Bb, 64, 0, stream>>>(pm, ps, partial, vmean, M_top, dvh, dvl, map);

  gemm_dout<<<dim3(DV_ROWS / 128, 4), 256, 0, stream>>>(
      dvh, dvl, WTh + (size_t)1536 * 512, WTl + (size_t)1536 * 512, dout);

  assemble_kernel<<<M_ROWS / 4, 256, 0, stream>>>(map, dout, bo, out);
}

// Round 18
// 167.977 us; speedup vs baseline: 1.0130x; 1.0130x over previous
//
#include <hip/hip_runtime.h>
#include <math.h>

namespace {

constexpr int Bb = 4, Nn = 2048, Cc = 512, Hh = 8, Dd = 64, Ss = 40, Uu = 40;
constexpr int M_ROWS = Bb * Nn; // 8192
constexpr int BH = Bb * Hh;     // 32
constexpr int DV_ROWS = 1408;   // 1280 attn rows + 4 vmean rows, padded to 11*128

typedef __attribute__((ext_vector_type(8))) short short8;
typedef __attribute__((ext_vector_type(4))) float f32x4;

__device__ inline unsigned short f2bf(float f) {
  union { float f; unsigned u; } v; v.f = f;
  unsigned r = (v.u + 0x7fffu + ((v.u >> 16) & 1u)) >> 16;
  return (unsigned short)r;
}
__device__ inline float bf2f(unsigned short h) {
  union { unsigned u; float f; } v; v.u = ((unsigned)h) << 16;
  return v.f;
}

// ---------- split x into bf16 hi/lo AND build transposed split weights ----------
__global__ __launch_bounds__(256) void convert_all(
    const float* __restrict__ x, const float* __restrict__ Wq,
    const float* __restrict__ Wk, const float* __restrict__ Wv,
    const float* __restrict__ Wo,
    unsigned short* __restrict__ xh, unsigned short* __restrict__ xl,
    unsigned short* __restrict__ WTh, unsigned short* __restrict__ WTl)
{
  if (blockIdx.x < 4096) {
    size_t i = ((size_t)blockIdx.x * 256 + threadIdx.x) * 4;
    float4 v = *(const float4*)(x + i);
    ushort4 h, l;
    h.x = f2bf(v.x); l.x = f2bf(v.x - bf2f(h.x));
    h.y = f2bf(v.y); l.y = f2bf(v.y - bf2f(h.y));
    h.z = f2bf(v.z); l.z = f2bf(v.z - bf2f(h.z));
    h.w = f2bf(v.w); l.w = f2bf(v.w - bf2f(h.w));
    *(ushort4*)(xh + i) = h;
    *(ushort4*)(xl + i) = l;
  } else {
    int wb = blockIdx.x - 4096;       // 0..255
    int which = wb >> 6;
    int tile = wb & 63;
    int tr = tile >> 3, tc = tile & 7;
    const float* Wsrc = which == 0 ? Wq : (which == 1 ? Wk : (which == 2 ? Wv : Wo));
    __shared__ float tileS[64][65];
    int t = threadIdx.x;
    int r0 = t >> 4;
    int c0 = (t & 15) * 4;
    #pragma unroll
    for (int i = 0; i < 4; ++i) {
      int r = r0 + i * 16;
      float4 v = *(const float4*)(Wsrc + (size_t)(tr * 64 + r) * 512 + tc * 64 + c0);
      tileS[r][c0] = v.x; tileS[r][c0 + 1] = v.y;
      tileS[r][c0 + 2] = v.z; tileS[r][c0 + 3] = v.w;
    }
    __syncthreads();
    #pragma unroll
    for (int i = 0; i < 4; ++i) {
      int c = r0 + i * 16;
      float4 v = make_float4(tileS[c0][c], tileS[c0 + 1][c],
                             tileS[c0 + 2][c], tileS[c0 + 3][c]);
      ushort4 hh, ll;
      hh.x = f2bf(v.x); ll.x = f2bf(v.x - bf2f(hh.x));
      hh.y = f2bf(v.y); ll.y = f2bf(v.y - bf2f(hh.y));
      hh.z = f2bf(v.z); ll.z = f2bf(v.z - bf2f(hh.z));
      hh.w = f2bf(v.w); ll.w = f2bf(v.w - bf2f(hh.w));
      size_t off = (size_t)(which * 512 + tc * 64 + c) * 512 + tr * 64 + c0;
      *(ushort4*)(WTh + off) = hh;
      *(ushort4*)(WTl + off) = ll;
    }
  }
}

// ---------- QKV GEMM: 256x128 tile, 512 threads, R12-proven (47us) ----------
__global__ __launch_bounds__(512) void gemm_qkv(
    const unsigned short* __restrict__ xh, const unsigned short* __restrict__ xl,
    const unsigned short* __restrict__ WThp, const unsigned short* __restrict__ WTlp,
    const float* __restrict__ bq, const float* __restrict__ bk, const float* __restrict__ bv,
    float* __restrict__ o0, float* __restrict__ o1, float* __restrict__ o2)
{
  __shared__ __align__(16) unsigned short Ah[256 * 32];
  __shared__ __align__(16) unsigned short Al[256 * 32];
  __shared__ __align__(16) unsigned short Bh[128 * 32];
  __shared__ __align__(16) unsigned short Bl[128 * 32];
  int tid = threadIdx.x;
  int lane = tid & 63, w = tid >> 6;
  int bm = blockIdx.x * 256, bn = blockIdx.y * 128;

  f32x4 acc[4][4];
  #pragma unroll
  for (int i = 0; i < 4; ++i)
    #pragma unroll
    for (int j = 0; j < 4; ++j)
      #pragma unroll
      for (int r = 0; r < 4; ++r) acc[i][j][r] = 0.f;

  int wm = (w >> 1) * 64, wn = (w & 1) * 64;
  int lm = lane & 15, lg = lane >> 4;

  int srow = tid >> 2;                       // 0..127
  int cs = (tid & 3) ^ ((srow >> 1) & 3);    // pre-swizzled source chunk
  size_t a0 = (size_t)(bm + srow) * 512 + cs * 8;
  size_t a1 = a0 + (size_t)128 * 512;
  size_t b0 = (size_t)(bn + srow) * 512 + cs * 8;
  unsigned d0 = w * 1024;

#define GLDS(gp, lp) __builtin_amdgcn_global_load_lds( \
    (const __attribute__((address_space(1))) void*)(gp), \
    (__attribute__((address_space(3))) void*)(lp), 16, 0, 0)

  for (int kt = 0; kt < 16; ++kt) {
    int k0 = kt * 32;
    GLDS(xh   + a0 + k0, (char*)Ah + d0);
    GLDS(xh   + a1 + k0, (char*)Ah + 8192 + d0);
    GLDS(xl   + a0 + k0, (char*)Al + d0);
    GLDS(xl   + a1 + k0, (char*)Al + 8192 + d0);
    GLDS(WThp + b0 + k0, (char*)Bh + d0);
    GLDS(WTlp + b0 + k0, (char*)Bl + d0);
    __syncthreads();

    short8 afh[4], bgh[4], afl[4], bgl[4];
    #pragma unroll
    for (int i = 0; i < 4; ++i) {
      int R = wm + i * 16 + lm;
      afh[i] = *(const short8*)(Ah + R * 32 + ((lg ^ ((R >> 1) & 3)) * 8));
    }
    #pragma unroll
    for (int j = 0; j < 4; ++j) {
      int R = wn + j * 16 + lm;
      bgh[j] = *(const short8*)(Bh + R * 32 + ((lg ^ ((R >> 1) & 3)) * 8));
    }
    #pragma unroll
    for (int i = 0; i < 4; ++i)
      #pragma unroll
      for (int j = 0; j < 4; ++j)
        acc[i][j] = __builtin_amdgcn_mfma_f32_16x16x32_bf16(afh[i], bgh[j], acc[i][j], 0, 0, 0);

    #pragma unroll
    for (int i = 0; i < 4; ++i) {
      int R = wm + i * 16 + lm;
      afl[i] = *(const short8*)(Al + R * 32 + ((lg ^ ((R >> 1) & 3)) * 8));
    }
    #pragma unroll
    for (int i = 0; i < 4; ++i)
      #pragma unroll
      for (int j = 0; j < 4; ++j)
        acc[i][j] = __builtin_amdgcn_mfma_f32_16x16x32_bf16(afl[i], bgh[j], acc[i][j], 0, 0, 0);

    #pragma unroll
    for (int j = 0; j < 4; ++j) {
      int R = wn + j * 16 + lm;
      bgl[j] = *(const short8*)(Bl + R * 32 + ((lg ^ ((R >> 1) & 3)) * 8));
    }
    #pragma unroll
    for (int i = 0; i < 4; ++i)
      #pragma unroll
      for (int j = 0; j < 4; ++j)
        acc[i][j] = __builtin_amdgcn_mfma_f32_16x16x32_bf16(afh[i], bgl[j], acc[i][j], 0, 0, 0);

    __syncthreads();
  }
#undef GLDS

  #pragma unroll
  for (int j = 0; j < 4; ++j) {
    int n = bn + wn + j * 16 + lm;
    float bias = n < 512 ? bq[n] : (n < 1024 ? bk[n - 512] : bv[n - 1024]);
    int tensor = n >> 9, h = (n >> 6) & 7, d = n & 63;
    float* op = tensor == 0 ? o0 : (tensor == 1 ? o1 : o2);
    #pragma unroll
    for (int i = 0; i < 4; ++i) {
      #pragma unroll
      for (int r = 0; r < 4; ++r) {
        int m = bm + wm + i * 16 + lg * 4 + r;
        int b = m >> 11, nn = m & 2047;
        op[((size_t)(b * Hh + h) * Nn + nn) * Dd + d] = acc[i][j][r] + bias;
      }
    }
  }
}

// ---------- dout GEMM: 128x128 tile, 256 threads (R9-proven geometry) ----------
__global__ __launch_bounds__(256) void gemm_dout(
    const unsigned short* __restrict__ xh, const unsigned short* __restrict__ xl,
    const unsigned short* __restrict__ WThp, const unsigned short* __restrict__ WTlp,
    float* __restrict__ o0)
{
  __shared__ __align__(16) unsigned short Ah[128 * 32];
  __shared__ __align__(16) unsigned short Al[128 * 32];
  __shared__ __align__(16) unsigned short Bh[128 * 32];
  __shared__ __align__(16) unsigned short Bl[128 * 32];
  int tid = threadIdx.x;
  int lane = tid & 63, w = tid >> 6;
  int bm = blockIdx.x * 128, bn = blockIdx.y * 128;

  f32x4 acc[4][4];
  #pragma unroll
  for (int i = 0; i < 4; ++i)
    #pragma unroll
    for (int j = 0; j < 4; ++j)
      #pragma unroll
      for (int r = 0; r < 4; ++r) acc[i][j][r] = 0.f;

  int wm = (w >> 1) * 64, wn = (w & 1) * 64;
  int lm = lane & 15, lg = lane >> 4;

  int srow = lane >> 2;
  int row0 = w * 16 + srow;
  int row1 = row0 + 64;
  int cs0 = (lane & 3) ^ ((row0 >> 1) & 3);
  int cs1 = (lane & 3) ^ ((row1 >> 1) & 3);
  size_t a0 = (size_t)(bm + row0) * 512 + cs0 * 8;
  size_t a1 = (size_t)(bm + row1) * 512 + cs1 * 8;
  size_t b0 = (size_t)(bn + row0) * 512 + cs0 * 8;
  size_t b1 = (size_t)(bn + row1) * 512 + cs1 * 8;
  unsigned d0 = w * 1024;

#define GLDS(gp, lp) __builtin_amdgcn_global_load_lds( \
    (const __attribute__((address_space(1))) void*)(gp), \
    (__attribute__((address_space(3))) void*)(lp), 16, 0, 0)

  for (int kt = 0; kt < 16; ++kt) {
    int k0 = kt * 32;
    GLDS(xh   + a0 + k0, (char*)Ah + d0);
    GLDS(xh   + a1 + k0, (char*)Ah + 4096 + d0);
    GLDS(xl   + a0 + k0, (char*)Al + d0);
    GLDS(xl   + a1 + k0, (char*)Al + 4096 + d0);
    GLDS(WThp + b0 + k0, (char*)Bh + d0);
    GLDS(WThp + b1 + k0, (char*)Bh + 4096 + d0);
    GLDS(WTlp + b0 + k0, (char*)Bl + d0);
    GLDS(WTlp + b1 + k0, (char*)Bl + 4096 + d0);
    __syncthreads();

    short8 afh[4], bgh[4], afl[4], bgl[4];
    #pragma unroll
    for (int i = 0; i < 4; ++i) {
      int R = wm + i * 16 + lm;
      afh[i] = *(const short8*)(Ah + R * 32 + ((lg ^ ((R >> 1) & 3)) * 8));
    }
    #pragma unroll
    for (int j = 0; j < 4; ++j) {
      int R = wn + j * 16 + lm;
      bgh[j] = *(const short8*)(Bh + R * 32 + ((lg ^ ((R >> 1) & 3)) * 8));
    }
    #pragma unroll
    for (int i = 0; i < 4; ++i)
      #pragma unroll
      for (int j = 0; j < 4; ++j)
        acc[i][j] = __builtin_amdgcn_mfma_f32_16x16x32_bf16(afh[i], bgh[j], acc[i][j], 0, 0, 0);

    #pragma unroll
    for (int i = 0; i < 4; ++i) {
      int R = wm + i * 16 + lm;
      afl[i] = *(const short8*)(Al + R * 32 + ((lg ^ ((R >> 1) & 3)) * 8));
    }
    #pragma unroll
    for (int i = 0; i < 4; ++i)
      #pragma unroll
      for (int j = 0; j < 4; ++j)
        acc[i][j] = __builtin_amdgcn_mfma_f32_16x16x32_bf16(afl[i], bgh[j], acc[i][j], 0, 0, 0);

    #pragma unroll
    for (int j = 0; j < 4; ++j) {
      int R = wn + j * 16 + lm;
      bgl[j] = *(const short8*)(Bl + R * 32 + ((lg ^ ((R >> 1) & 3)) * 8));
    }
    #pragma unroll
    for (int i = 0; i < 4; ++i)
      #pragma unroll
      for (int j = 0; j < 4; ++j)
        acc[i][j] = __builtin_amdgcn_mfma_f32_16x16x32_bf16(afh[i], bgl[j], acc[i][j], 0, 0, 0);

    __syncthreads();
  }
#undef GLDS

  #pragma unroll
  for (int j = 0; j < 4; ++j) {
    int n = bn + wn + j * 16 + lm;
    #pragma unroll
    for (int i = 0; i < 4; ++i) {
      #pragma unroll
      for (int r = 0; r < 4; ++r) {
        int m = bm + wm + i * 16 + lg * 4 + r;
        o0[(size_t)m * 512 + n] = acc[i][j][r];
      }
    }
  }
}

// ---------- sampled QK^T -> M (blocks 0..2047) + vmean/map-init (2048..2079) ----------
__global__ __launch_bounds__(256) void sampled_vmean_kernel(
    const float* __restrict__ q, const float* __restrict__ k,
    const int* __restrict__ idx, float* __restrict__ Mout,
    const float* __restrict__ v, float* __restrict__ vmean, int* __restrict__ map)
{
  int p = blockIdx.x;
  int t = threadIdx.x;
  if (p >= 2048) {
    int bh = p - 2048;
    for (int i = t; i < Nn; i += 256) map[bh * Nn + i] = -1;
    int d = t & 63, chunk = t >> 6;
    const float* base = v + (size_t)bh * Nn * Dd;
    float s = 0.f;
    for (int n = chunk * 512; n < (chunk + 1) * 512; ++n) s += base[(size_t)n * Dd + d];
    __shared__ float part[4][64];
    part[chunk][d] = s;
    __syncthreads();
    if (t < 64)
      vmean[bh * Dd + t] = (part[0][t] + part[1][t] + part[2][t] + part[3][t]) * (1.f / (float)Nn);
    return;
  }
  int xcd = p & 7, j = p >> 3;
  int chunk = j & 63;
  int bh = (j >> 6) * 8 + xcd;
  int w = t >> 6, lane = t & 63;
  int g = lane >> 2, dq = lane & 3;

  const float* kb = k + (size_t)bh * Nn * Dd;

  for (int li = 0; li < 8; ++li) {
    int l = chunk * 32 + w * 8 + li;
    const float* qrow = q + ((size_t)bh * Nn + l) * Dd + dq * 4;
    float4 qv[4];
    #pragma unroll
    for (int i = 0; i < 4; ++i) qv[i] = *(const float4*)(qrow + i * 16);
    float mx = -INFINITY, sm = 0.f;
    #pragma unroll
    for (int pass = 0; pass < 3; ++pass) {
      int s = pass * 16 + g;
      bool valid = (s < Ss);
      float dot = 0.f;
      if (valid) {
        int kr = idx[l * Ss + s];
        const float* krow = kb + (size_t)kr * Dd + dq * 4;
        #pragma unroll
        for (int i = 0; i < 4; ++i) {
          float4 kv = *(const float4*)(krow + i * 16);
          dot += kv.x * qv[i].x + kv.y * qv[i].y + kv.z * qv[i].z + kv.w * qv[i].w;
        }
      }
      dot += __shfl_xor(dot, 1);
      dot += __shfl_xor(dot, 2);
      if (valid) { mx = fmaxf(mx, dot); sm += dot; }
    }
    #pragma unroll
    for (int o = 4; o < 64; o <<= 1) {
      mx = fmaxf(mx, __shfl_xor(mx, o));
      sm += __shfl_xor(sm, o);
    }
    if (lane == 0) Mout[(size_t)bh * Nn + l] = mx - sm * (1.f / (float)Nn);
  }
}

// ---------- top-40 per (b,h): exact radix-select ----------
__global__ __launch_bounds__(256) void topk_kernel(
    const float* __restrict__ Min, int* __restrict__ M_top)
{
  int bh = blockIdx.x, t = threadIdx.x;
  __shared__ unsigned keys[2048];
  __shared__ unsigned hist[256];
  __shared__ unsigned cum[257];
  __shared__ unsigned sh_b, sh_k, sh_cnt, sh_eqcnt;
  __shared__ int eqlist[2048];

  #pragma unroll
  for (int j = 0; j < 8; ++j) {
    int ix = t + j * 256;
    unsigned u = __float_as_uint(Min[(size_t)bh * Nn + ix]);
    keys[ix] = u ^ (((unsigned)((int)u >> 31)) | 0x80000000u);
  }
  if (t == 0) { sh_k = Uu; sh_cnt = 0; sh_eqcnt = 0; }
  if (t == 255) cum[256] = 0;
  __syncthreads();

  unsigned known = 0;
  for (int shift = 24; shift >= 0; shift -= 8) {
    hist[t] = 0;
    __syncthreads();
    unsigned mask_hi = (shift == 24) ? 0u : (0xFFFFFFFFu << (shift + 8));
    #pragma unroll
    for (int j = 0; j < 8; ++j) {
      unsigned key = keys[t + j * 256];
      if ((key & mask_hi) == known)
        atomicAdd(&hist[(key >> shift) & 255], 1u);
    }
    __syncthreads();
    cum[t] = hist[t];
    __syncthreads();
    for (int off = 1; off < 256; off <<= 1) {
      unsigned add = (t + off < 256) ? cum[t + off] : 0u;
      __syncthreads();
      cum[t] += add;
      __syncthreads();
    }
    unsigned kcur = sh_k;
    if (cum[t] >= kcur && cum[t + 1] < kcur) sh_b = (unsigned)t;
    __syncthreads();
    unsigned b = sh_b;
    if (t == 0) sh_k = kcur - cum[b + 1];
    known |= (b << shift);
    __syncthreads();
  }

  unsigned T = known;
  #pragma unroll
  for (int j = 0; j < 8; ++j) {
    int ix = t + j * 256;
    unsigned key = keys[ix];
    if (key > T) {
      unsigned slot = atomicAdd(&sh_cnt, 1u);
      M_top[bh * Uu + slot] = ix;
    } else if (key == T) {
      unsigned e = atomicAdd(&sh_eqcnt, 1u);
      eqlist[e] = ix;
    }
  }
  __syncthreads();
  if (t == 0) {
    unsigned kk = sh_k;
    unsigned m = sh_eqcnt;
    unsigned base = sh_cnt;
    for (unsigned r = 0; r < kk; ++r) {
      int best = 0x7FFFFFFF, bj = 0;
      for (unsigned j2 = 0; j2 < m; ++j2)
        if (eqlist[j2] < best) { best = eqlist[j2]; bj = (int)j2; }
      M_top[bh * Uu + base + r] = best;
      eqlist[bj] = 0x7FFFFFFF;
    }
  }
}

// ---------- fused scores+softmax+PV partials, per (64-col chunk, bh) ----------
__global__ __launch_bounds__(256) void fused_attn_kernel(
    const float* __restrict__ q, const float* __restrict__ k, const float* __restrict__ v,
    const int* __restrict__ M_top, float* __restrict__ pm, float* __restrict__ ps,
    float* __restrict__ partial)
{
  int chunk = blockIdx.x, bh = blockIdx.y, t = threadIdx.x;
  __shared__ float qs[40][64];
  __shared__ float S[40][64];
  if (t < 160) {
    int u = t >> 2, p = (t & 3) * 16;
    int r = M_top[bh * Uu + u];
    const float4* src = (const float4*)(q + ((size_t)bh * Nn + r) * Dd + p);
    *(float4*)&qs[u][p + 0]  = src[0];
    *(float4*)&qs[u][p + 4]  = src[1];
    *(float4*)&qs[u][p + 8]  = src[2];
    *(float4*)&qs[u][p + 12] = src[3];
  }
  __syncthreads();

  int nl = t & 63, w = t >> 6;
  {
    int n = chunk * 64 + nl;
    const float4* krow = (const float4*)(k + ((size_t)bh * Nn + n) * Dd);
    float acc[10];
    #pragma unroll
    for (int uu = 0; uu < 10; ++uu) acc[uu] = 0.f;
    #pragma unroll
    for (int d4 = 0; d4 < 16; ++d4) {
      float4 kv = krow[d4];
      #pragma unroll
      for (int uu = 0; uu < 10; ++uu) {
        float4 qv = *(const float4*)&qs[w * 10 + uu][d4 * 4];
        acc[uu] += qv.x * kv.x + qv.y * kv.y + qv.z * kv.z + qv.w * kv.w;
      }
    }
    #pragma unroll
    for (int uu = 0; uu < 10; ++uu) S[w * 10 + uu][nl] = acc[uu] * 0.125f;
  }

  #pragma unroll
  for (int r = 0; r < 10; ++r) {
    int u = w * 10 + r;
    float v0 = S[u][nl];
    float m = v0;
    #pragma unroll
    for (int o = 1; o < 64; o <<= 1) m = fmaxf(m, __shfl_xor(m, o));
    float e0 = expf(v0 - m);
    S[u][nl] = e0;
    float sum = e0;
    #pragma unroll
    for (int o = 1; o < 64; o <<= 1) sum += __shfl_xor(sum, o);
    if (nl == 0) {
      pm[(bh * 32 + chunk) * Uu + u] = m;
      ps[(bh * 32 + chunk) * Uu + u] = sum;
    }
  }

  float acc2[10];
  #pragma unroll
  for (int uu = 0; uu < 10; ++uu) acc2[uu] = 0.f;
  const float* vb = v + ((size_t)bh * Nn + chunk * 64) * Dd + nl;
  for (int i = 0; i < 64; ++i) {
    float vv = vb[(size_t)i * Dd];
    #pragma unroll
    for (int uu = 0; uu < 10; ++uu) acc2[uu] = fmaf(S[w * 10 + uu][i], vv, acc2[uu]);
  }
  #pragma unroll
  for (int uu = 0; uu < 10; ++uu) {
    int u = w * 10 + uu;
    partial[(((size_t)bh * Uu + u) * 32 + chunk) * 64 + nl] = acc2[uu];
  }
}

// ---------- combine partials -> dvF rows; blocks >=1280 emit vmean rows ----------
__global__ __launch_bounds__(64) void combine_lite(
    const float* __restrict__ pm, const float* __restrict__ ps,
    const float* __restrict__ partial, const float* __restrict__ vmean,
    const int* __restrict__ M_top,
    unsigned short* __restrict__ dvh, unsigned short* __restrict__ dvl,
    int* __restrict__ map)
{
  int bhu = blockIdx.x;
  int lane = threadIdx.x;

  if (bhu >= BH * Uu) {
    int b = bhu - BH * Uu;
    #pragma unroll
    for (int cc = 0; cc < 8; ++cc) {
      float v = vmean[(b * 8 + cc) * 64 + lane];
      unsigned short hb = f2bf(v);
      dvh[(size_t)bhu * 512 + cc * 64 + lane] = hb;
      dvl[(size_t)bhu * 512 + cc * 64 + lane] = f2bf(v - bf2f(hb));
    }
    return;
  }

  int bh = bhu / Uu, u = bhu % Uu, h = bh & 7;
  float pmv[32];
  float m = -INFINITY;
  #pragma unroll
  for (int c = 0; c < 32; ++c) {
    pmv[c] = pm[(bh * 32 + c) * Uu + u];
    m = fmaxf(m, pmv[c]);
  }
  float w32[32], Z = 0.f;
  #pragma unroll
  for (int c = 0; c < 32; ++c) {
    w32[c] = expf(pmv[c] - m);
    Z += w32[c] * ps[(bh * 32 + c) * Uu + u];
  }

  const float* pb = partial + (size_t)bhu * 2048;
  float s = 0.f;
  #pragma unroll
  for (int c = 0; c < 32; ++c)
    s = fmaf(pb[c * 64 + lane], w32[c], s);

  float dv = s / Z - vmean[bh * Dd + lane];
  unsigned short hbits = f2bf(dv);
  unsigned short lbits = f2bf(dv - bf2f(hbits));

  #pragma unroll
  for (int cc = 0; cc < 8; ++cc) {
    int c = cc * 64 + lane;
    bool mine = (cc == h);
    dvh[(size_t)bhu * 512 + c] = mine ? hbits : (unsigned short)0;
    dvl[(size_t)bhu * 512 + c] = mine ? lbits : (unsigned short)0;
  }
  if (lane == 0) map[bh * Nn + M_top[bhu]] = bhu;
}

// ---------- assemble out rows (base = dout row 1280+b, + bo) ----------
__global__ __launch_bounds__(256) void assemble_kernel(
    const int* __restrict__ map, const float* __restrict__ dout,
    const float* __restrict__ bo, float* __restrict__ out)
{
  int t = threadIdx.x;
  int row = blockIdx.x * 4 + (t >> 6);
  int lane = t & 63;
  int b = row >> 11, n = row & 2047;
  const float* bp = dout + (size_t)(BH * Uu + b) * 512;
  float4 a0 = *(const float4*)(bp + lane * 4);
  float4 a1 = *(const float4*)(bp + 256 + lane * 4);
  float4 o0 = *(const float4*)(bo + lane * 4);
  float4 o1 = *(const float4*)(bo + 256 + lane * 4);
  a0.x += o0.x; a0.y += o0.y; a0.z += o0.z; a0.w += o0.w;
  a1.x += o1.x; a1.y += o1.y; a1.z += o1.z; a1.w += o1.w;
  for (int h = 0; h < 8; ++h) {
    int mi = map[(b * Hh + h) * Nn + n];
    if (mi >= 0) {
      const float* dp = dout + (size_t)mi * 512;
      float4 d0 = *(const float4*)(dp + lane * 4);
      float4 d1 = *(const float4*)(dp + 256 + lane * 4);
      a0.x += d0.x; a0.y += d0.y; a0.z += d0.z; a0.w += d0.w;
      a1.x += d1.x; a1.y += d1.y; a1.z += d1.z; a1.w += d1.w;
    }
  }
  *(float4*)(out + (size_t)row * 512 + lane * 4) = a0;
  *(float4*)(out + (size_t)row * 512 + 256 + lane * 4) = a1;
}

} // namespace

extern "C" void kernel_launch(void* const* d_in, const int* in_sizes, int n_in,
                              void* d_out, int out_size, void* d_ws, size_t ws_size,
                              hipStream_t stream) {
  const float* x  = (const float*)d_in[0];
  const float* Wq = (const float*)d_in[1];
  const float* bq = (const float*)d_in[2];
  const float* Wk = (const float*)d_in[3];
  const float* bk = (const float*)d_in[4];
  const float* Wv = (const float*)d_in[5];
  const float* bv = (const float*)d_in[6];
  const float* Wo = (const float*)d_in[7];
  const float* bo = (const float*)d_in[8];
  const int* idx  = (const int*)d_in[9];
  float* out = (float*)d_out;

  float* ws = (float*)d_ws;
  float* q      = ws;                       // 4,194,304 f
  float* kbuf   = ws + 4194304;
  float* vbuf   = ws + 8388608;
  float* Mbuf   = ws + 12582912;            // 65,536 f
  float* vmean  = ws + 12648448;            // 2,048 f
  float* pm     = ws + 12650496;            // 40,960 f [32][32][40]
  float* ps     = ws + 12691456;            // 40,960 f
  float* dout   = ws + 12732416;            // 720,896 f [1408][512]
  int*   M_top  = (int*)(ws + 13453312);    // 1,280
  int*   map    = (int*)(ws + 13454592);    // 65,536
  unsigned short* dvh = (unsigned short*)(ws + 13520128); // 1408*512 u16
  unsigned short* dvl = (unsigned short*)(ws + 13880576);
  unsigned short* xh  = (unsigned short*)(ws + 14241024); // 8192*512 u16
  unsigned short* xl  = (unsigned short*)(ws + 16338176);
  unsigned short* WTh = (unsigned short*)(ws + 18435328); // 2048*512 u16
  unsigned short* WTl = (unsigned short*)(ws + 18959616);
  float* partial = ws + 14241024;           // overlays xh/xl after gemm_qkv

  convert_all<<<4096 + 256, 256, 0, stream>>>(x, Wq, Wk, Wv, Wo, xh, xl, WTh, WTl);

  gemm_qkv<<<dim3(32, 12), 512, 0, stream>>>(
      xh, xl, WTh, WTl, bq, bk, bv, q, kbuf, vbuf);

  sampled_vmean_kernel<<<2048 + 32, 256, 0, stream>>>(
      q, kbuf, idx, Mbuf, vbuf, vmean, map);

  topk_kernel<<<BH, 256, 0, stream>>>(Mbuf, M_top);

  fused_attn_kernel<<<dim3(32, BH), 256, 0, stream>>>(q, kbuf, vbuf, M_top, pm, ps, partial);

  combine_lite<<<BH * Uu + Bb, 64, 0, stream>>>(pm, ps, partial, vmean, M_top, dvh, dvl, map);

  gemm_dout<<<dim3(DV_ROWS / 128, 4), 256, 0, stream>>>(
      dvh, dvl, WTh + (size_t)1536 * 512, WTl + (size_t)1536 * 512, dout);

  assemble_kernel<<<M_ROWS / 4, 256, 0, stream>>>(map, dout, bo, out);
}